// Round 4
// baseline (175.296 us; speedup 1.0000x reference)
//
#include <hip/hip_runtime.h>

// B=128, V=300, MAX_VISITS=510, D=256, VOCAB=50000, MAX_DAYS=365.
#define MAXV 510
#define D4 64  // D/4 float4 per row

// Native clang vector type: __builtin_nontemporal_store requires a real
// vector type, not HIP's struct-based float4.
typedef float floatx4 __attribute__((ext_vector_type(4)));

// ---- Kernel 1: scatter slot->visit inverse map + per-visit segment offsets ----
// (inv is pre-initialized to -1 via hipMemsetAsync(0xFF))
__global__ __launch_bounds__(256) void build_maps(
    const int* __restrict__ c2v,
    const int* __restrict__ person,
    const int* __restrict__ slot,
    int* __restrict__ inv,     // [B*MAXV]
    int* __restrict__ off,     // [total_visits+1]
    int total_codes, int total_visits)
{
    int v = blockIdx.x * blockDim.x + threadIdx.x;
    if (v >= total_visits) return;
    inv[person[v] * MAXV + slot[v]] = v;
    // lower_bound(c2v, v) over sorted segment ids (c2v ~1.7 MB, L2-resident)
    int lo = 0, hi = total_codes;
    while (lo < hi) {
        int m = (lo + hi) >> 1;
        if (c2v[m] < v) lo = m + 1; else hi = m;
    }
    off[v] = lo;
    if (v == 0) off[total_visits] = total_codes;
}

// ---- Kernel 2: fused pad-fill + segment-sum + time embedding ----
// One wave per output slot; lane l owns dims [4l, 4l+4).
// Output stores are nontemporal: the 67 MB write stream must not evict the
// 51 MB emb table from L2/L3 (round-2 FETCH was 4x ideal => thrash theory).
__global__ __launch_bounds__(256) void fused_kernel(
    const int* __restrict__ all_codes,
    const float* __restrict__ times,
    const floatx4* __restrict__ emb,  // [VOCAB, D4]
    const floatx4* __restrict__ pad,  // [D4]
    const floatx4* __restrict__ tsc,  // [32] = 128 timescales
    const int* __restrict__ inv,      // [nslots]
    const int* __restrict__ off,      // [total_visits+1]
    floatx4* __restrict__ out,        // [nslots, D4]
    int nslots)
{
    const int tid = threadIdx.x;
    const int w = tid >> 6;
    const int lane = tid & 63;
    const int slot_id = blockIdx.x * 4 + w;
    if (slot_id >= nslots) return;

    const int v = inv[slot_id];
    if (v < 0) {
        __builtin_nontemporal_store(pad[lane], &out[slot_id * D4 + lane]);
        return;
    }

    const int lo = off[v];
    const int hi = off[v + 1];
    const int cnt = hi - lo;

    floatx4 acc = (floatx4)(0.f);
    // Outer: 64 codes at a time via one lane-load; inner: 4-wide chunks so
    // 4 independent row-gathers are in flight before the first waitcnt (MLP=4).
    for (int base = 0; base < cnt; base += 64) {
        const int n = min(cnt - base, 64);
        const int mycode = (lane < n) ? all_codes[lo + base + lane]
                                      : all_codes[lo];
        for (int j = 0; j < n; j += 4) {
            const int i1 = min(j + 1, n - 1);
            const int i2 = min(j + 2, n - 1);
            const int i3 = min(j + 3, n - 1);
            const int c0 = __shfl(mycode, j);
            const int c1 = __shfl(mycode, i1);
            const int c2 = __shfl(mycode, i2);
            const int c3 = __shfl(mycode, i3);
            const floatx4 e0 = emb[c0 * D4 + lane];
            const floatx4 e1 = emb[c1 * D4 + lane];
            const floatx4 e2 = emb[c2 * D4 + lane];
            const floatx4 e3 = emb[c3 * D4 + lane];
            acc += e0;
            if (j + 1 < n) acc += e1;
            if (j + 2 < n) acc += e2;
            if (j + 3 < n) acc += e3;
        }
    }

    float t = times[v];
    t = fminf(fmaxf(t, 0.f), 364.f);
    const floatx4 ts = tsc[lane & 31];
    floatx4 te;
    if (lane < 32) {
        te.x = sinf(t * ts.x); te.y = sinf(t * ts.y);
        te.z = sinf(t * ts.z); te.w = sinf(t * ts.w);
    } else {
        te.x = cosf(t * ts.x); te.y = cosf(t * ts.y);
        te.z = cosf(t * ts.z); te.w = cosf(t * ts.w);
    }

    __builtin_nontemporal_store(acc + te, &out[slot_id * D4 + lane]);
}

extern "C" void kernel_launch(void* const* d_in, const int* in_sizes, int n_in,
                              void* d_out, int out_size, void* d_ws, size_t ws_size,
                              hipStream_t stream) {
    const int*   all_codes = (const int*)d_in[0];
    const int*   c2v       = (const int*)d_in[1];
    const int*   person    = (const int*)d_in[2];
    const int*   slot      = (const int*)d_in[3];
    const float* times     = (const float*)d_in[4];
    const float* emb       = (const float*)d_in[5];
    const float* pad       = (const float*)d_in[6];
    const float* tsc       = (const float*)d_in[7];

    const int total_codes  = in_sizes[0];
    const int total_visits = in_sizes[2];
    const int nslots       = out_size / 256;   // B * MAXV

    int* inv = (int*)d_ws;                     // [nslots]
    int* off = inv + nslots;                   // [total_visits+1]

    // inv := -1 (0xFFFFFFFF) without a dedicated kernel launch
    (void)hipMemsetAsync(inv, 0xFF, (size_t)nslots * sizeof(int), stream);

    build_maps<<<(total_visits + 255) / 256, 256, 0, stream>>>(
        c2v, person, slot, inv, off, total_codes, total_visits);

    fused_kernel<<<(nslots + 3) / 4, 256, 0, stream>>>(
        all_codes, times, (const floatx4*)emb, (const floatx4*)pad,
        (const floatx4*)tsc, inv, off, (floatx4*)d_out, nslots);
}